// Round 8
// baseline (440.981 us; speedup 1.0000x reference)
//
#include <hip/hip_runtime.h>

#define F 128
#define H 64
#define O 16

#define BSHIFT 7
#define BSZ 128       // nodes per coarse bucket
#define NSUB 8        // privatized cursor sub-regions per bucket
#define SUBCAP 768    // capacity per (bucket,sub): mean 512, +11 sigma
#define ACHUNK 8192   // edges per bucketA block

typedef _Float16 half8_t __attribute__((ext_vector_type(8)));

// ---------- CSR build: LDS-aggregated multisplit, privatized reservation ----------
__global__ void k_bcur2(int* __restrict__ bcur, int NC) {
    int i = blockIdx.x * blockDim.x + threadIdx.x;
    if (i < NC) bcur[i] = i * SUBCAP;
}

__global__ __launch_bounds__(512) void k_bucketA(const int* __restrict__ src,
                                                 const int* __restrict__ dstv,
                                                 int* __restrict__ bcur,
                                                 int* __restrict__ bdata, int E) {
    __shared__ int hist[1024];
    for (int t = threadIdx.x; t < 1024; t += 512) hist[t] = 0;
    __syncthreads();
    int base = blockIdx.x * ACHUNK;
    int end = min(base + ACHUNK, E);
    for (int i = base + threadIdx.x; i < end; i += 512) {
        atomicAdd(&hist[dstv[i] >> BSHIFT], 1);
    }
    __syncthreads();
    // reserve ranges in this block's private sub-region cursors (8x fewer
    // contenders per address: hot-address atomics are ~437cy serialized)
    int sub = blockIdx.x & (NSUB - 1);
    for (int b = threadIdx.x; b < 1024; b += 512) {
        int c = hist[b];
        if (c > 0) hist[b] = atomicAdd(&bcur[b * NSUB + sub], c);
    }
    __syncthreads();
    for (int i = base + threadIdx.x; i < end; i += 512) {
        int d = dstv[i];
        int b = d >> BSHIFT;
        int pos = atomicAdd(&hist[b], 1);
        bdata[pos] = (src[i] << BSHIFT) | (d & (BSZ - 1));
    }
}

__global__ __launch_bounds__(256) void k_bdeg(const int* __restrict__ bdata,
                                              const int* __restrict__ bcur,
                                              int* __restrict__ deg, int N) {
    __shared__ int h[BSZ];
    int b = blockIdx.x;
    int node0 = b << BSHIFT;
    int nloc = min(BSZ, N - node0);
    for (int t = threadIdx.x; t < BSZ; t += 256) h[t] = 0;
    __syncthreads();
    for (int s = 0; s < NSUB; s++) {
        int start = (b * NSUB + s) * SUBCAP;
        int end = bcur[b * NSUB + s];
        for (int p = start + threadIdx.x; p < end; p += 256)
            atomicAdd(&h[bdata[p] & (BSZ - 1)], 1);
    }
    __syncthreads();
    for (int t = threadIdx.x; t < nloc; t += 256) deg[node0 + t] = h[t];
}

__global__ void k_dis(const int* __restrict__ deg, float* __restrict__ dis, int N) {
    int i = blockIdx.x * blockDim.x + threadIdx.x;
    if (i < N) dis[i] = rsqrtf((float)deg[i] + 1.0f);
}

__global__ void k_scan1(const int* __restrict__ deg, int* __restrict__ local,
                        int* __restrict__ partials, int N) {
    __shared__ int s[256];
    int tid = threadIdx.x;
    int i = blockIdx.x * 256 + tid;
    int v = (i < N) ? deg[i] : 0;
    s[tid] = v;
    __syncthreads();
    for (int off = 1; off < 256; off <<= 1) {
        int t = (tid >= off) ? s[tid - off] : 0;
        __syncthreads();
        s[tid] += t;
        __syncthreads();
    }
    if (i < N) local[i] = s[tid] - v;
    if (tid == 255) partials[blockIdx.x] = s[255];
}

__global__ void k_scan2(int* __restrict__ partials, int NB) {
    __shared__ int s[1024];
    int tid = threadIdx.x;
    int v = (tid < NB) ? partials[tid] : 0;
    s[tid] = v;
    __syncthreads();
    for (int off = 1; off < 1024; off <<= 1) {
        int t = (tid >= off) ? s[tid - off] : 0;
        __syncthreads();
        s[tid] += t;
        __syncthreads();
    }
    partials[tid] = s[tid] - v;
}

__global__ void k_scan3(int* __restrict__ row_ptr, const int* __restrict__ partials,
                        int N, int E) {
    int i = blockIdx.x * blockDim.x + threadIdx.x;
    if (i < N) {
        row_ptr[i] += partials[i >> 8];
    } else if (i == N) {
        row_ptr[N] = E;
    }
}

__global__ __launch_bounds__(256) void k_bplace(const int* __restrict__ bdata,
                                                const int* __restrict__ bcur,
                                                const int* __restrict__ row_ptr,
                                                int* __restrict__ col, int N) {
    __shared__ int cur[BSZ];
    int b = blockIdx.x;
    int node0 = b << BSHIFT;
    int nloc = min(BSZ, N - node0);
    for (int t = threadIdx.x; t < nloc; t += 256) cur[t] = row_ptr[node0 + t];
    __syncthreads();
    for (int s = 0; s < NSUB; s++) {
        int start = (b * NSUB + s) * SUBCAP;
        int end = bcur[b * NSUB + s];
        for (int p = start + threadIdx.x; p < end; p += 256) {
            int v = bdata[p];
            int pos = atomicAdd(&cur[v & (BSZ - 1)], 1);
            col[pos] = v >> BSHIFT;
        }
    }
}

// ---------- layer 1: h1p = fp16( (x @ W1) * dis[row] ) ----------
// 4-wave blocks, 64 rows/block; wave w computes cols [16w,16w+16) for all k.
// Per k: one 64B s_load (pipelinable) + 16 FMAs; no cross-wave reduction.
__global__ __launch_bounds__(256) void k_gemm1(const float* __restrict__ x,
                                               const float* __restrict__ W1,
                                               const float* __restrict__ dis,
                                               _Float16* __restrict__ h1p, int N) {
    __shared__ float xs[64 * 129];  // stride 129: lane*129+k -> bank (lane+k)%32
    int tid = threadIdx.x;
    int row0 = blockIdx.x * 64;
    // stage x[row0..+64][0..128), coalesced float4 reads, scalar LDS writes
#pragma unroll
    for (int i = 0; i < 8; i++) {
        int idx = i * 256 + tid;         // 2048 float4 total
        int r = idx >> 5;                // 32 float4 per row
        int c = (idx & 31) * 4;
        int rr = row0 + r; if (rr >= N) rr = N - 1;
        float4 v = *(const float4*)(x + (size_t)rr * F + c);
        xs[r * 129 + c + 0] = v.x;
        xs[r * 129 + c + 1] = v.y;
        xs[r * 129 + c + 2] = v.z;
        xs[r * 129 + c + 3] = v.w;
    }
    __syncthreads();
    int wave = tid >> 6, lane = tid & 63;
    int c0 = wave * 16;
    float acc[16];
#pragma unroll
    for (int j = 0; j < 16; j++) acc[j] = 0.f;
    const float* xrow = xs + lane * 129;
#pragma unroll 4
    for (int k = 0; k < F; k++) {
        float a = xrow[k];
        const float* wrow = W1 + (size_t)k * H + c0;  // wave-uniform 64B -> SGPRs
#pragma unroll
        for (int j = 0; j < 16; j++) acc[j] = fmaf(a, wrow[j], acc[j]);
    }
    int row = row0 + lane;
    if (row < N) {
        float d = dis[row];
        half8_t* orow = (half8_t*)(h1p + (size_t)row * H + c0);
#pragma unroll
        for (int j0 = 0; j0 < 16; j0 += 8) {
            half8_t o;
#pragma unroll
            for (int j = 0; j < 8; j++) o[j] = (_Float16)(acc[j0 + j] * d);
            orow[j0 / 8] = o;
        }
    }
}

// ---------- layer 1 aggregation: 1 wave/node, 8 edges in flight, fp16 rows ----------
__global__ __launch_bounds__(256) void k_gather1(const _Float16* __restrict__ h1p,
                                                 const float* __restrict__ dis,
                                                 const int* __restrict__ row_ptr,
                                                 const int* __restrict__ col,
                                                 const float* __restrict__ b1,
                                                 float* __restrict__ z, int N) {
    int node = blockIdx.x * 4 + (threadIdx.x >> 6);
    if (node >= N) return;
    int lane = threadIdx.x & 63;
    int g = lane >> 3;   // edge group 0..7
    int t = lane & 7;    // 8-feature slot
    const half8_t* hp = (const half8_t*)h1p;
    float acc[8];
#pragma unroll
    for (int j = 0; j < 8; j++) acc[j] = 0.f;
    int e = row_ptr[node + 1];
    for (int p = row_ptr[node] + g; p < e; p += 8) {
        int s = col[p];
        half8_t v = hp[(size_t)s * 8 + t];
#pragma unroll
        for (int j = 0; j < 8; j++) acc[j] += (float)v[j];
    }
#pragma unroll
    for (int off = 8; off < 64; off <<= 1) {
#pragma unroll
        for (int j = 0; j < 8; j++) acc[j] += __shfl_xor(acc[j], off);
    }
    if (g == 0) {
        float dn = dis[node];
        half8_t self = hp[(size_t)node * 8 + t];
        float o[8];
#pragma unroll
        for (int j = 0; j < 8; j++)
            o[j] = fmaxf(fmaf(acc[j] + (float)self[j], dn, b1[t * 8 + j]), 0.f);
        float4* zp = (float4*)(z + (size_t)node * H + t * 8);
        zp[0] = float4{o[0], o[1], o[2], o[3]};
        zp[1] = float4{o[4], o[5], o[6], o[7]};
    }
}

// ---------- layer 2: h2p = fp16( (z @ W2) * dis[row] ) ----------
__global__ __launch_bounds__(64) void k_gemm2(const float* __restrict__ z,
                                              const float* __restrict__ W2,
                                              const float* __restrict__ dis,
                                              _Float16* __restrict__ h2p, int N) {
    __shared__ float zs[64 * 65];
    int lane = threadIdx.x;
    int row0 = blockIdx.x * 64;
#pragma unroll
    for (int i = 0; i < 16; i++) {
        int r = i * 4 + (lane >> 4);
        int c = (lane & 15) * 4;
        int rr = row0 + r; if (rr >= N) rr = N - 1;
        float4 v = *(const float4*)(z + (size_t)rr * H + c);
        zs[r * 65 + c + 0] = v.x;
        zs[r * 65 + c + 1] = v.y;
        zs[r * 65 + c + 2] = v.z;
        zs[r * 65 + c + 3] = v.w;
    }
    __syncthreads();
    float acc[O];
#pragma unroll
    for (int c = 0; c < O; c++) acc[c] = 0.f;
#pragma unroll 4
    for (int k = 0; k < H; k++) {
        float a = zs[lane * 65 + k];
        const float* wrow = W2 + (size_t)k * O;  // wave-uniform
#pragma unroll
        for (int c = 0; c < O; c++) acc[c] = fmaf(a, wrow[c], acc[c]);
    }
    int row = row0 + lane;
    if (row < N) {
        float d = dis[row];
        half8_t* orow = (half8_t*)(h2p + (size_t)row * O);
#pragma unroll
        for (int c0 = 0; c0 < O; c0 += 8) {
            half8_t o;
#pragma unroll
            for (int j = 0; j < 8; j++) o[j] = (_Float16)(acc[c0 + j] * d);
            orow[c0 / 8] = o;
        }
    }
}

// ---------- layer 2 aggregation: 1 wave/node, 32 edges in flight, fp16 rows ----------
__global__ __launch_bounds__(256) void k_gather2(const _Float16* __restrict__ h2p,
                                                 const float* __restrict__ dis,
                                                 const int* __restrict__ row_ptr,
                                                 const int* __restrict__ col,
                                                 const float* __restrict__ b2,
                                                 float* __restrict__ z2, int N) {
    int node = blockIdx.x * 4 + (threadIdx.x >> 6);
    if (node >= N) return;
    int lane = threadIdx.x & 63;
    int g = lane >> 1;   // edge group 0..31
    int t = lane & 1;    // 8-feature slot
    const half8_t* hp = (const half8_t*)h2p;
    float acc[8];
#pragma unroll
    for (int j = 0; j < 8; j++) acc[j] = 0.f;
    int e = row_ptr[node + 1];
    for (int p = row_ptr[node] + g; p < e; p += 32) {
        int s = col[p];
        half8_t v = hp[(size_t)s * 2 + t];
#pragma unroll
        for (int j = 0; j < 8; j++) acc[j] += (float)v[j];
    }
#pragma unroll
    for (int off = 2; off < 64; off <<= 1) {
#pragma unroll
        for (int j = 0; j < 8; j++) acc[j] += __shfl_xor(acc[j], off);
    }
    if (g == 0) {
        float dn = dis[node];
        half8_t self = hp[(size_t)node * 2 + t];
        float o[8];
#pragma unroll
        for (int j = 0; j < 8; j++)
            o[j] = fmaf(acc[j] + (float)self[j], dn, b2[t * 8 + j]);
        float4* zp = (float4*)(z2 + (size_t)node * O + t * 8);
        zp[0] = float4{o[0], o[1], o[2], o[3]};
        zp[1] = float4{o[4], o[5], o[6], o[7]};
    }
}

// ---------- link prediction logits: 4 lanes per pair ----------
__global__ __launch_bounds__(256) void k_logits(const float* __restrict__ z2,
                                                const int* __restrict__ pos,
                                                const int* __restrict__ neg,
                                                float* __restrict__ out, int P, int Q) {
    int tid = blockIdx.x * 256 + threadIdx.x;
    int i = tid >> 2;
    if (i >= P + Q) return;
    int k = tid & 3;
    int a, b;
    if (i < P) { a = pos[i]; b = pos[P + i]; }
    else       { int t = i - P; a = neg[t]; b = neg[Q + t]; }
    float4 va = *(const float4*)(z2 + (size_t)a * O + k * 4);
    float4 vb = *(const float4*)(z2 + (size_t)b * O + k * 4);
    float r = va.x * vb.x + va.y * vb.y + va.z * vb.z + va.w * vb.w;
    r += __shfl_xor(r, 1);
    r += __shfl_xor(r, 2);
    if (k == 0) out[i] = r;
}

extern "C" void kernel_launch(void* const* d_in, const int* in_sizes, int n_in,
                              void* d_out, int out_size, void* d_ws, size_t ws_size,
                              hipStream_t stream) {
    const float* x   = (const float*)d_in[0];
    const int*   ei  = (const int*)d_in[1];
    const int*   pos = (const int*)d_in[2];
    const int*   neg = (const int*)d_in[3];
    const float* W1  = (const float*)d_in[4];
    const float* b1  = (const float*)d_in[5];
    const float* W2  = (const float*)d_in[6];
    const float* b2  = (const float*)d_in[7];
    float* out = (float*)d_out;

    int N = in_sizes[0] / F;
    int E = in_sizes[1] / 2;
    int P = in_sizes[2] / 2;
    int Q = in_sizes[3] / 2;
    const int* src  = ei;
    const int* dstv = ei + E;

    int NB  = (N + 255) / 256;        // scan blocks, <= 1024
    int Npad = NB * 256;
    int Epad = (E + 63) & ~63;
    int NBK = (N + BSZ - 1) / BSZ;    // coarse buckets
    int NC  = NBK * NSUB;             // privatized cursors

    // workspace layout (byte-exact; all region sizes multiples of 256B)
    char* w = (char*)d_ws;
    int*   deg      = (int*)w;        w += (size_t)Npad * 4;
    float* dis      = (float*)w;      w += (size_t)Npad * 4;
    int*   row_ptr  = (int*)w;        w += (size_t)(Npad + 256) * 4;
    int*   bcur     = (int*)w;        w += 8192 * 4;           // NC <= 8192
    int*   partials = (int*)w;        w += 1024 * 4;
    int*   col      = (int*)w;        w += (size_t)Epad * 4;
    // h1p (fp16, 12.8MB) aliases bdata (NC*SUBCAP*4 = 19.2MB); reserve max
    _Float16* h1p   = (_Float16*)w;
    int*      bdata = (int*)w;
    size_t h1b = (size_t)N * H * 2, bdb = (size_t)NC * SUBCAP * 4;
    w += (h1b > bdb ? h1b : bdb);
    float*    z     = (float*)w;      w += (size_t)N * H * 4;
    _Float16* h2p   = (_Float16*)w;   w += (size_t)N * O * 2;
    float*    z2    = (float*)w;

    // CSR build: multisplit with privatized reservation cursors
    k_bcur2<<<(NC + 255) / 256, 256, 0, stream>>>(bcur, NC);
    k_bucketA<<<(E + ACHUNK - 1) / ACHUNK, 512, 0, stream>>>(src, dstv, bcur, bdata, E);
    k_bdeg<<<NBK, 256, 0, stream>>>(bdata, bcur, deg, N);
    k_dis<<<(N + 255) / 256, 256, 0, stream>>>(deg, dis, N);
    k_scan1<<<NB, 256, 0, stream>>>(deg, row_ptr, partials, N);
    k_scan2<<<1, 1024, 0, stream>>>(partials, NB);
    k_scan3<<<(N + 256) / 256, 256, 0, stream>>>(row_ptr, partials, N, E);
    k_bplace<<<NBK, 256, 0, stream>>>(bdata, bcur, row_ptr, col, N);

    // layer 1
    k_gemm1<<<(N + 63) / 64, 256, 0, stream>>>(x, W1, dis, h1p, N);
    k_gather1<<<(N + 3) / 4, 256, 0, stream>>>(h1p, dis, row_ptr, col, b1, z, N);

    // layer 2
    k_gemm2<<<(N + 63) / 64, 64, 0, stream>>>(z, W2, dis, h2p, N);
    k_gather2<<<(N + 3) / 4, 256, 0, stream>>>(h2p, dis, row_ptr, col, b2, z2, N);

    // logits
    k_logits<<<((P + Q) * 4 + 255) / 256, 256, 0, stream>>>(z2, pos, neg, out, P, Q);
}

// Round 9
// 345.161 us; speedup vs baseline: 1.2776x; 1.2776x over previous
//
#include <hip/hip_runtime.h>

#define F 128
#define H 64
#define O 16

#define BSHIFT 7
#define BSZ 128       // nodes per coarse bucket
#define NSUB 8        // privatized cursor sub-regions per bucket
#define SUBCAP 768    // capacity per (bucket,sub): mean 512, +11 sigma
#define ACHUNK 8192   // edges per bucketA block
#define XS 136        // LDS row stride in f16 (272B = 17*16B: aligned, 2-way only)

typedef _Float16 half8_t __attribute__((ext_vector_type(8)));
typedef _Float16 half4_t __attribute__((ext_vector_type(4)));
typedef float f32x4 __attribute__((ext_vector_type(4)));

// ---------- CSR build: LDS-aggregated multisplit, privatized reservation ----------
__global__ void k_bcur2(int* __restrict__ bcur, int NC) {
    int i = blockIdx.x * blockDim.x + threadIdx.x;
    if (i < NC) bcur[i] = i * SUBCAP;
}

__global__ __launch_bounds__(512) void k_bucketA(const int* __restrict__ src,
                                                 const int* __restrict__ dstv,
                                                 int* __restrict__ bcur,
                                                 int* __restrict__ bdata, int E) {
    __shared__ int hist[1024];
    for (int t = threadIdx.x; t < 1024; t += 512) hist[t] = 0;
    __syncthreads();
    int base = blockIdx.x * ACHUNK;
    int end = min(base + ACHUNK, E);
    for (int i = base + threadIdx.x; i < end; i += 512) {
        atomicAdd(&hist[dstv[i] >> BSHIFT], 1);
    }
    __syncthreads();
    int sub = blockIdx.x & (NSUB - 1);
    for (int b = threadIdx.x; b < 1024; b += 512) {
        int c = hist[b];
        if (c > 0) hist[b] = atomicAdd(&bcur[b * NSUB + sub], c);
    }
    __syncthreads();
    for (int i = base + threadIdx.x; i < end; i += 512) {
        int d = dstv[i];
        int b = d >> BSHIFT;
        int pos = atomicAdd(&hist[b], 1);
        bdata[pos] = (src[i] << BSHIFT) | (d & (BSZ - 1));
    }
}

__global__ __launch_bounds__(256) void k_bdeg(const int* __restrict__ bdata,
                                              const int* __restrict__ bcur,
                                              int* __restrict__ deg, int N) {
    __shared__ int h[BSZ];
    int b = blockIdx.x;
    int node0 = b << BSHIFT;
    int nloc = min(BSZ, N - node0);
    for (int t = threadIdx.x; t < BSZ; t += 256) h[t] = 0;
    __syncthreads();
    for (int s = 0; s < NSUB; s++) {
        int start = (b * NSUB + s) * SUBCAP;
        int end = bcur[b * NSUB + s];
        for (int p = start + threadIdx.x; p < end; p += 256)
            atomicAdd(&h[bdata[p] & (BSZ - 1)], 1);
    }
    __syncthreads();
    for (int t = threadIdx.x; t < nloc; t += 256) deg[node0 + t] = h[t];
}

__global__ void k_dis(const int* __restrict__ deg, float* __restrict__ dis, int N) {
    int i = blockIdx.x * blockDim.x + threadIdx.x;
    if (i < N) dis[i] = rsqrtf((float)deg[i] + 1.0f);
}

__global__ void k_scan1(const int* __restrict__ deg, int* __restrict__ local,
                        int* __restrict__ partials, int N) {
    __shared__ int s[256];
    int tid = threadIdx.x;
    int i = blockIdx.x * 256 + tid;
    int v = (i < N) ? deg[i] : 0;
    s[tid] = v;
    __syncthreads();
    for (int off = 1; off < 256; off <<= 1) {
        int t = (tid >= off) ? s[tid - off] : 0;
        __syncthreads();
        s[tid] += t;
        __syncthreads();
    }
    if (i < N) local[i] = s[tid] - v;
    if (tid == 255) partials[blockIdx.x] = s[255];
}

__global__ void k_scan2(int* __restrict__ partials, int NB) {
    __shared__ int s[1024];
    int tid = threadIdx.x;
    int v = (tid < NB) ? partials[tid] : 0;
    s[tid] = v;
    __syncthreads();
    for (int off = 1; off < 1024; off <<= 1) {
        int t = (tid >= off) ? s[tid - off] : 0;
        __syncthreads();
        s[tid] += t;
        __syncthreads();
    }
    partials[tid] = s[tid] - v;
}

__global__ void k_scan3(int* __restrict__ row_ptr, const int* __restrict__ partials,
                        int N, int E) {
    int i = blockIdx.x * blockDim.x + threadIdx.x;
    if (i < N) {
        row_ptr[i] += partials[i >> 8];
    } else if (i == N) {
        row_ptr[N] = E;
    }
}

__global__ __launch_bounds__(256) void k_bplace(const int* __restrict__ bdata,
                                                const int* __restrict__ bcur,
                                                const int* __restrict__ row_ptr,
                                                int* __restrict__ col, int N) {
    __shared__ int cur[BSZ];
    int b = blockIdx.x;
    int node0 = b << BSHIFT;
    int nloc = min(BSZ, N - node0);
    for (int t = threadIdx.x; t < nloc; t += 256) cur[t] = row_ptr[node0 + t];
    __syncthreads();
    for (int s = 0; s < NSUB; s++) {
        int start = (b * NSUB + s) * SUBCAP;
        int end = bcur[b * NSUB + s];
        for (int p = start + threadIdx.x; p < end; p += 256) {
            int v = bdata[p];
            int pos = atomicAdd(&cur[v & (BSZ - 1)], 1);
            col[pos] = v >> BSHIFT;
        }
    }
}

// ---------- W1 prep: wt_hi/wt_lo = transposed fp16 hi/lo split, [n][k] ----------
__global__ void k_wprep(const float* __restrict__ W1, _Float16* __restrict__ wt_hi,
                        _Float16* __restrict__ wt_lo) {
    int idx = blockIdx.x * 256 + threadIdx.x;  // 64*128 = 8192
    int c = idx >> 7, k = idx & 127;
    float w = W1[k * H + c];
    _Float16 hi = (_Float16)w;
    wt_hi[idx] = hi;
    wt_lo[idx] = (_Float16)(w - (float)hi);
}

// ---------- layer 1: h1p = fp16( (x @ W1) * dis[row] ), MFMA hi/lo split ----------
// fp32-exact: x_hi*w_hi + x_hi*w_lo + x_lo*w_hi in fp32 MFMA accumulators.
// A-frag: A[m=lane&15][k=quad*8+j]; B-frag from wt[n][k]: B[k=quad*8+j][n=lane&15].
// C/D: col=lane&15, row=quad*4+reg (verified m89/m120 layouts).
__global__ __launch_bounds__(256) void k_gemm1(const float* __restrict__ x,
                                               const _Float16* __restrict__ wt_hi,
                                               const _Float16* __restrict__ wt_lo,
                                               const float* __restrict__ dis,
                                               _Float16* __restrict__ h1p, int N) {
    __shared__ _Float16 xh[64 * XS], xl[64 * XS], wh[64 * XS], wl[64 * XS];
    int tid = threadIdx.x;
    int row0 = blockIdx.x * 64;
    // stage x rows (fp32 -> hi/lo fp16), coalesced float4 reads
#pragma unroll
    for (int i = 0; i < 8; i++) {
        int idx = i * 256 + tid;          // 2048 float4
        int r = idx >> 5;
        int c = (idx & 31) * 4;
        int rr = row0 + r; if (rr >= N) rr = N - 1;
        float4 v = *(const float4*)(x + (size_t)rr * F + c);
        half4_t h = {(_Float16)v.x, (_Float16)v.y, (_Float16)v.z, (_Float16)v.w};
        half4_t l = {(_Float16)(v.x - (float)h[0]), (_Float16)(v.y - (float)h[1]),
                     (_Float16)(v.z - (float)h[2]), (_Float16)(v.w - (float)h[3])};
        *(half4_t*)(xh + r * XS + c) = h;
        *(half4_t*)(xl + r * XS + c) = l;
    }
    // stage wt (already [n][k] f16): 1024 half8 per array
#pragma unroll
    for (int i = 0; i < 4; i++) {
        int idx = i * 256 + tid;          // 1024
        int c = idx >> 4;
        int k8 = (idx & 15) * 8;
        *(half8_t*)(wh + c * XS + k8) = *(const half8_t*)(wt_hi + c * 128 + k8);
        *(half8_t*)(wl + c * XS + k8) = *(const half8_t*)(wt_lo + c * 128 + k8);
    }
    __syncthreads();
    int wv = tid >> 6, lane = tid & 63;
    int m = lane & 15, qd = lane >> 4;
    const _Float16* xhp = xh + (wv * 16 + m) * XS;
    const _Float16* xlp = xl + (wv * 16 + m) * XS;
    f32x4 acc[4] = {f32x4{0,0,0,0}, f32x4{0,0,0,0}, f32x4{0,0,0,0}, f32x4{0,0,0,0}};
#pragma unroll
    for (int kc = 0; kc < 4; kc++) {
        int ko = kc * 32 + qd * 8;
        half8_t ah = *(const half8_t*)(xhp + ko);
        half8_t al = *(const half8_t*)(xlp + ko);
#pragma unroll
        for (int nt = 0; nt < 4; nt++) {
            half8_t bh = *(const half8_t*)(wh + (nt * 16 + m) * XS + ko);
            half8_t bl = *(const half8_t*)(wl + (nt * 16 + m) * XS + ko);
            acc[nt] = __builtin_amdgcn_mfma_f32_16x16x32_f16(ah, bh, acc[nt], 0, 0, 0);
            acc[nt] = __builtin_amdgcn_mfma_f32_16x16x32_f16(ah, bl, acc[nt], 0, 0, 0);
            acc[nt] = __builtin_amdgcn_mfma_f32_16x16x32_f16(al, bh, acc[nt], 0, 0, 0);
        }
    }
#pragma unroll
    for (int reg = 0; reg < 4; reg++) {
        int row = row0 + wv * 16 + qd * 4 + reg;
        if (row < N) {
            float d = dis[row];
#pragma unroll
            for (int nt = 0; nt < 4; nt++) {
                h1p[(size_t)row * H + nt * 16 + m] = (_Float16)(acc[nt][reg] * d);
            }
        }
    }
}

// ---------- layer 1 aggregation: 1 wave/node, 8 edges in flight, fp16 rows ----------
__global__ __launch_bounds__(256) void k_gather1(const _Float16* __restrict__ h1p,
                                                 const float* __restrict__ dis,
                                                 const int* __restrict__ row_ptr,
                                                 const int* __restrict__ col,
                                                 const float* __restrict__ b1,
                                                 float* __restrict__ z, int N) {
    int node = blockIdx.x * 4 + (threadIdx.x >> 6);
    if (node >= N) return;
    int lane = threadIdx.x & 63;
    int g = lane >> 3;   // edge group 0..7
    int t = lane & 7;    // 8-feature slot
    const half8_t* hp = (const half8_t*)h1p;
    float acc[8];
#pragma unroll
    for (int j = 0; j < 8; j++) acc[j] = 0.f;
    int e = row_ptr[node + 1];
    for (int p = row_ptr[node] + g; p < e; p += 8) {
        int s = col[p];
        half8_t v = hp[(size_t)s * 8 + t];
#pragma unroll
        for (int j = 0; j < 8; j++) acc[j] += (float)v[j];
    }
#pragma unroll
    for (int off = 8; off < 64; off <<= 1) {
#pragma unroll
        for (int j = 0; j < 8; j++) acc[j] += __shfl_xor(acc[j], off);
    }
    if (g == 0) {
        float dn = dis[node];
        half8_t self = hp[(size_t)node * 8 + t];
        float o[8];
#pragma unroll
        for (int j = 0; j < 8; j++)
            o[j] = fmaxf(fmaf(acc[j] + (float)self[j], dn, b1[t * 8 + j]), 0.f);
        float4* zp = (float4*)(z + (size_t)node * H + t * 8);
        zp[0] = float4{o[0], o[1], o[2], o[3]};
        zp[1] = float4{o[4], o[5], o[6], o[7]};
    }
}

// ---------- layer 2: h2p = fp16( (z @ W2) * dis[row] ) ----------
__global__ __launch_bounds__(64) void k_gemm2(const float* __restrict__ z,
                                              const float* __restrict__ W2,
                                              const float* __restrict__ dis,
                                              _Float16* __restrict__ h2p, int N) {
    __shared__ float zs[64 * 65];
    int lane = threadIdx.x;
    int row0 = blockIdx.x * 64;
#pragma unroll
    for (int i = 0; i < 16; i++) {
        int r = i * 4 + (lane >> 4);
        int c = (lane & 15) * 4;
        int rr = row0 + r; if (rr >= N) rr = N - 1;
        float4 v = *(const float4*)(z + (size_t)rr * H + c);
        zs[r * 65 + c + 0] = v.x;
        zs[r * 65 + c + 1] = v.y;
        zs[r * 65 + c + 2] = v.z;
        zs[r * 65 + c + 3] = v.w;
    }
    __syncthreads();
    float acc[O];
#pragma unroll
    for (int c = 0; c < O; c++) acc[c] = 0.f;
#pragma unroll 4
    for (int k = 0; k < H; k++) {
        float a = zs[lane * 65 + k];
        const float* wrow = W2 + (size_t)k * O;  // uniform (depends only on k) -> s_load
#pragma unroll
        for (int c = 0; c < O; c++) acc[c] = fmaf(a, wrow[c], acc[c]);
    }
    int row = row0 + lane;
    if (row < N) {
        float d = dis[row];
        half8_t* orow = (half8_t*)(h2p + (size_t)row * O);
#pragma unroll
        for (int c0 = 0; c0 < O; c0 += 8) {
            half8_t o;
#pragma unroll
            for (int j = 0; j < 8; j++) o[j] = (_Float16)(acc[c0 + j] * d);
            orow[c0 / 8] = o;
        }
    }
}

// ---------- layer 2 aggregation: 1 wave/node, 32 edges in flight, fp16 rows ----------
__global__ __launch_bounds__(256) void k_gather2(const _Float16* __restrict__ h2p,
                                                 const float* __restrict__ dis,
                                                 const int* __restrict__ row_ptr,
                                                 const int* __restrict__ col,
                                                 const float* __restrict__ b2,
                                                 float* __restrict__ z2, int N) {
    int node = blockIdx.x * 4 + (threadIdx.x >> 6);
    if (node >= N) return;
    int lane = threadIdx.x & 63;
    int g = lane >> 1;   // edge group 0..31
    int t = lane & 1;    // 8-feature slot
    const half8_t* hp = (const half8_t*)h2p;
    float acc[8];
#pragma unroll
    for (int j = 0; j < 8; j++) acc[j] = 0.f;
    int e = row_ptr[node + 1];
    for (int p = row_ptr[node] + g; p < e; p += 32) {
        int s = col[p];
        half8_t v = hp[(size_t)s * 2 + t];
#pragma unroll
        for (int j = 0; j < 8; j++) acc[j] += (float)v[j];
    }
#pragma unroll
    for (int off = 2; off < 64; off <<= 1) {
#pragma unroll
        for (int j = 0; j < 8; j++) acc[j] += __shfl_xor(acc[j], off);
    }
    if (g == 0) {
        float dn = dis[node];
        half8_t self = hp[(size_t)node * 2 + t];
        float o[8];
#pragma unroll
        for (int j = 0; j < 8; j++)
            o[j] = fmaf(acc[j] + (float)self[j], dn, b2[t * 8 + j]);
        float4* zp = (float4*)(z2 + (size_t)node * O + t * 8);
        zp[0] = float4{o[0], o[1], o[2], o[3]};
        zp[1] = float4{o[4], o[5], o[6], o[7]};
    }
}

// ---------- link prediction logits: 4 lanes per pair ----------
__global__ __launch_bounds__(256) void k_logits(const float* __restrict__ z2,
                                                const int* __restrict__ pos,
                                                const int* __restrict__ neg,
                                                float* __restrict__ out, int P, int Q) {
    int tid = blockIdx.x * 256 + threadIdx.x;
    int i = tid >> 2;
    if (i >= P + Q) return;
    int k = tid & 3;
    int a, b;
    if (i < P) { a = pos[i]; b = pos[P + i]; }
    else       { int t = i - P; a = neg[t]; b = neg[Q + t]; }
    float4 va = *(const float4*)(z2 + (size_t)a * O + k * 4);
    float4 vb = *(const float4*)(z2 + (size_t)b * O + k * 4);
    float r = va.x * vb.x + va.y * vb.y + va.z * vb.z + va.w * vb.w;
    r += __shfl_xor(r, 1);
    r += __shfl_xor(r, 2);
    if (k == 0) out[i] = r;
}

extern "C" void kernel_launch(void* const* d_in, const int* in_sizes, int n_in,
                              void* d_out, int out_size, void* d_ws, size_t ws_size,
                              hipStream_t stream) {
    const float* x   = (const float*)d_in[0];
    const int*   ei  = (const int*)d_in[1];
    const int*   pos = (const int*)d_in[2];
    const int*   neg = (const int*)d_in[3];
    const float* W1  = (const float*)d_in[4];
    const float* b1  = (const float*)d_in[5];
    const float* W2  = (const float*)d_in[6];
    const float* b2  = (const float*)d_in[7];
    float* out = (float*)d_out;

    int N = in_sizes[0] / F;
    int E = in_sizes[1] / 2;
    int P = in_sizes[2] / 2;
    int Q = in_sizes[3] / 2;
    const int* src  = ei;
    const int* dstv = ei + E;

    int NB  = (N + 255) / 256;        // scan blocks, <= 1024
    int Npad = NB * 256;
    int Epad = (E + 63) & ~63;
    int NBK = (N + BSZ - 1) / BSZ;    // coarse buckets
    int NC  = NBK * NSUB;             // privatized cursors

    // workspace layout (byte-exact; all region sizes multiples of 256B)
    char* w = (char*)d_ws;
    int*   deg      = (int*)w;        w += (size_t)Npad * 4;
    float* dis      = (float*)w;      w += (size_t)Npad * 4;
    int*   row_ptr  = (int*)w;        w += (size_t)(Npad + 256) * 4;
    int*   bcur     = (int*)w;        w += 8192 * 4;           // NC <= 8192
    int*   partials = (int*)w;        w += 1024 * 4;
    int*   col      = (int*)w;        w += (size_t)Epad * 4;
    // h1p (fp16, 12.8MB) aliases bdata (NC*SUBCAP*4 = 19.2MB); reserve max
    _Float16* h1p   = (_Float16*)w;
    int*      bdata = (int*)w;
    size_t h1b = (size_t)N * H * 2, bdb = (size_t)NC * SUBCAP * 4;
    w += (h1b > bdb ? h1b : bdb);
    float*    z     = (float*)w;      w += (size_t)N * H * 4;
    _Float16* h2p   = (_Float16*)w;   w += (size_t)N * O * 2;
    float*    z2    = (float*)w;      w += (size_t)N * O * 4;
    _Float16* wt_hi = (_Float16*)w;   w += (size_t)H * F * 2;  // 16KB
    _Float16* wt_lo = (_Float16*)w;

    // W1 split/transpose prep (tiny)
    k_wprep<<<(H * F + 255) / 256, 256, 0, stream>>>(W1, wt_hi, wt_lo);

    // CSR build: multisplit with privatized reservation cursors
    k_bcur2<<<(NC + 255) / 256, 256, 0, stream>>>(bcur, NC);
    k_bucketA<<<(E + ACHUNK - 1) / ACHUNK, 512, 0, stream>>>(src, dstv, bcur, bdata, E);
    k_bdeg<<<NBK, 256, 0, stream>>>(bdata, bcur, deg, N);
    k_dis<<<(N + 255) / 256, 256, 0, stream>>>(deg, dis, N);
    k_scan1<<<NB, 256, 0, stream>>>(deg, row_ptr, partials, N);
    k_scan2<<<1, 1024, 0, stream>>>(partials, NB);
    k_scan3<<<(N + 256) / 256, 256, 0, stream>>>(row_ptr, partials, N, E);
    k_bplace<<<NBK, 256, 0, stream>>>(bdata, bcur, row_ptr, col, N);

    // layer 1
    k_gemm1<<<(N + 63) / 64, 256, 0, stream>>>(x, wt_hi, wt_lo, dis, h1p, N);
    k_gather1<<<(N + 3) / 4, 256, 0, stream>>>(h1p, dis, row_ptr, col, b1, z, N);

    // layer 2
    k_gemm2<<<(N + 63) / 64, 64, 0, stream>>>(z, W2, dis, h2p, N);
    k_gather2<<<(N + 3) / 4, 256, 0, stream>>>(h2p, dis, row_ptr, col, b2, z2, N);

    // logits
    k_logits<<<((P + Q) * 4 + 255) / 256, 256, 0, stream>>>(z2, pos, neg, out, P, Q);
}